// Round 1
// baseline (324.451 us; speedup 1.0000x reference)
//
#include <hip/hip_runtime.h>
#include <hip/hip_bf16.h>
#include <math.h>

// Shapes (fixed)
// B=512, V=2, NX=1024, R=64, D=512, H=8, S=4, NC=2, HS=64, FIN=384

__device__ __forceinline__ float gelu_f(float x) {
    float x3 = x*x*x;
    return 0.5f*x*(1.0f + tanhf(0.7978845608028654f*(x + 0.044715f*x3)));
}

__device__ __forceinline__ float wave_sum(float x) {
    #pragma unroll
    for (int m = 32; m >= 1; m >>= 1) x += __shfl_xor(x, m, 64);
    return x;
}

// ---------------- generic tiled GEMM ----------------
// C[m,n] = epi( sum_k A[m,k]*B[k,n] + bias[n] )
// BTRANS: B stored N x K (ldb = row stride of N)
// EPI: 0 = +bias, 1 = gelu(+bias), 2 = +Add[m,n] (no bias)
template<bool BTRANS, int EPI>
__global__ __launch_bounds__(256) void gemm_k(
    const float* __restrict__ A, const float* __restrict__ B,
    const float* __restrict__ bias, const float* __restrict__ Add,
    float* __restrict__ C,
    int M, int N, int K, int lda, int ldb, int ldc, int ldadd,
    long aBS, long bBS, long biasBS, long addBS, long cBS)
{
    const int v = blockIdx.z;
    A += (long)v*aBS; B += (long)v*bBS; C += (long)v*cBS;
    if (bias) bias += (long)v*biasBS;
    if (Add)  Add  += (long)v*addBS;
    const int n0 = blockIdx.x*64, m0 = blockIdx.y*64;
    __shared__ float As[16][65];
    __shared__ float Bs[16][65];
    const int tid = threadIdx.x;
    const int tx = tid & 15, ty = tid >> 4;
    float acc[4][4] = {};
    for (int k0 = 0; k0 < K; k0 += 16) {
        {
            int kk = tid & 15, mm = tid >> 4;
            #pragma unroll
            for (int p = 0; p < 4; ++p)
                As[kk][mm + p*16] = A[(long)(m0 + mm + p*16)*lda + k0 + kk];
        }
        if (BTRANS) {
            int kk = tid & 15, nn = tid >> 4;
            #pragma unroll
            for (int p = 0; p < 4; ++p)
                Bs[kk][nn + p*16] = B[(long)(n0 + nn + p*16)*ldb + k0 + kk];
        } else {
            int nn = tid & 63, kk = tid >> 6;
            #pragma unroll
            for (int p = 0; p < 4; ++p)
                Bs[kk + p*4][nn] = B[(long)(k0 + kk + p*4)*ldb + n0 + nn];
        }
        __syncthreads();
        #pragma unroll
        for (int k = 0; k < 16; ++k) {
            float a[4], b[4];
            #pragma unroll
            for (int i = 0; i < 4; ++i) a[i] = As[k][ty*4+i];
            #pragma unroll
            for (int j = 0; j < 4; ++j) b[j] = Bs[k][tx*4+j];
            #pragma unroll
            for (int i = 0; i < 4; ++i)
                #pragma unroll
                for (int j = 0; j < 4; ++j)
                    acc[i][j] = fmaf(a[i], b[j], acc[i][j]);
        }
        __syncthreads();
    }
    #pragma unroll
    for (int i = 0; i < 4; ++i) {
        const int m = m0 + ty*4 + i;
        #pragma unroll
        for (int j = 0; j < 4; ++j) {
            const int n = n0 + tx*4 + j;
            float x = acc[i][j];
            if (EPI != 2) { if (bias) x += bias[n]; }
            if (EPI == 1) x = gelu_f(x);
            if (EPI == 2) x += Add[(long)m*ldadd + n];
            C[(long)m*ldc + n] = x;
        }
    }
}

// ---------------- control path: f = [sf(256), cf(128)] ----------------
__global__ __launch_bounds__(256) void control_k(
    const float* __restrict__ BC, const float* __restrict__ sb_w,
    const float* __restrict__ sb_b, const float* __restrict__ cm_w1,
    const float* __restrict__ cm_b1, const float* __restrict__ cm_w2,
    const float* __restrict__ cm_b2, float* __restrict__ f)
{
    const int b = blockIdx.x;
    const int tid = threadIdx.x;
    __shared__ float bc[6];
    __shared__ float cf1[64];
    if (tid < 6) bc[tid] = BC[b*6 + tid];
    __syncthreads();
    {
        int s = tid >> 6;
        f[(long)b*384 + tid] = gelu_f(bc[s]*sb_w[tid] + sb_b[tid]);
    }
    if (tid < 64) {
        cf1[tid] = gelu_f(bc[4]*cm_w1[tid] + bc[5]*cm_w1[64+tid] + cm_b1[tid]);
    }
    __syncthreads();
    if (tid < 128) {
        float acc = cm_b2[tid];
        #pragma unroll 8
        for (int i = 0; i < 64; ++i) acc = fmaf(cf1[i], cm_w2[i*128 + tid], acc);
        f[(long)b*384 + 256 + tid] = gelu_f(acc);
    }
}

// ---------------- K/V precompute: K[v,r,d] = sum_n Phi[v,n,r]*W[v,n,d] + b[v,d] ----------------
__global__ __launch_bounds__(256) void kv_pre_k(
    const float* __restrict__ Phi,
    const float* __restrict__ Wkw, const float* __restrict__ Wkb,
    const float* __restrict__ Wvw, const float* __restrict__ Wvb,
    float* __restrict__ Kws, float* __restrict__ Vws)
{
    const int z = blockIdx.z;
    const int v = z >> 1, which = z & 1;
    const float* W  = which ? Wvw : Wkw;
    const float* Wb = which ? Wvb : Wkb;
    float* C = which ? Vws : Kws;
    const int d  = blockIdx.x*64 + (threadIdx.x & 63);
    const int rb = blockIdx.y*16 + (threadIdx.x >> 6)*4;
    const float* Pp = Phi + (long)v*1024*64 + rb;   // wave-uniform -> s_load
    const float* Wp = W   + (long)v*1024*512 + d;
    float a0=0.f, a1=0.f, a2=0.f, a3=0.f;
    #pragma unroll 4
    for (int n = 0; n < 1024; ++n) {
        float wv = Wp[(long)n*512];
        const float* pr = Pp + (long)n*64;
        a0 = fmaf(pr[0], wv, a0);
        a1 = fmaf(pr[1], wv, a1);
        a2 = fmaf(pr[2], wv, a2);
        a3 = fmaf(pr[3], wv, a3);
    }
    const float bias = Wb[v*512 + d];
    float* Cp = C + ((long)v*64 + rb)*512 + d;
    Cp[0]    = a0 + bias;
    Cp[512]  = a1 + bias;
    Cp[1024] = a2 + bias;
    Cp[1536] = a3 + bias;
}

// ---------------- KV[v,h,k,l] = sum_r K[v,r,h*64+k]*V[v,r,h*64+l] ----------------
__global__ __launch_bounds__(256) void kv_outer_k(
    const float* __restrict__ Kws, const float* __restrict__ Vws,
    float* __restrict__ KV)
{
    const int z = blockIdx.x;
    const int v = z >> 3, h = z & 7;
    __shared__ float Ks[64][64];
    __shared__ float Vs[64][64];
    const int tid = threadIdx.x;
    for (int idx = tid; idx < 4096; idx += 256) {
        int r = idx >> 6, c = idx & 63;
        long off = ((long)v*64 + r)*512 + h*64 + c;
        Ks[r][c] = Kws[off];
        Vs[r][c] = Vws[off];
    }
    __syncthreads();
    const int tx = tid & 15, ty = tid >> 4;
    float acc[4][4] = {};
    #pragma unroll 4
    for (int r = 0; r < 64; ++r) {
        float a[4], bb[4];
        #pragma unroll
        for (int i = 0; i < 4; ++i) a[i] = Ks[r][ty*4+i];
        #pragma unroll
        for (int j = 0; j < 4; ++j) bb[j] = Vs[r][tx*4+j];
        #pragma unroll
        for (int i = 0; i < 4; ++i)
            #pragma unroll
            for (int j = 0; j < 4; ++j)
                acc[i][j] = fmaf(a[i], bb[j], acc[i][j]);
    }
    #pragma unroll
    for (int i = 0; i < 4; ++i)
        #pragma unroll
        for (int j = 0; j < 4; ++j)
            KV[(((long)v*8 + h)*64 + ty*4+i)*64 + tx*4+j] = acc[i][j];
}

// ---------------- attention constants: partial reductions over e-chunks ----------------
__global__ __launch_bounds__(256) void attn_parts_k(
    const float* __restrict__ KV, const float* __restrict__ Wq_w,
    const float* __restrict__ Wq_b, const float* __restrict__ attn_ow,
    const float* __restrict__ attn_ob, const float* __restrict__ proj_w,
    float* __restrict__ parts)
{
    const int v = blockIdx.x;
    const int ec = blockIdx.y;   // e-chunk of 64
    const int tid = threadIdx.x;
    __shared__ float Pv[512];
    __shared__ float Qv[512];
    // phase 1: Pvec/Qvec (cheap, recomputed per block)
    for (int dp = tid; dp < 512; dp += 256) {
        int h = dp >> 6, l = dp & 63;
        const float* kvp = KV + ((long)(v*8 + h)*64)*64 + l;
        const float* wq = Wq_w + v*512 + h*64;
        const float* wb = Wq_b + v*512 + h*64;
        float p = 0.f, q = 0.f;
        #pragma unroll 8
        for (int k = 0; k < 64; ++k) {
            float kv = kvp[(long)k*64];
            p = fmaf(wq[k], kv, p);
            q = fmaf(wb[k], kv, q);
        }
        Pv[dp] = p; Qv[dp] = q;
    }
    __syncthreads();
    // phase 2: Pw/Qw for 64 e's, then dot with proj_w
    const int e = ec*64 + (tid & 63);
    const int qd = tid >> 6;
    float pw = 0.f, qw = 0.f;
    const float* owp = attn_ow + (long)v*512*512 + e;
    #pragma unroll 8
    for (int d = qd*128; d < qd*128 + 128; ++d) {
        float wv = owp[(long)d*512];
        pw = fmaf(Pv[d], wv, pw);
        qw = fmaf(Qv[d], wv, qw);
    }
    __shared__ float red[2][256];
    red[0][tid] = pw; red[1][tid] = qw;
    __syncthreads();
    if (tid < 64) {
        float PW = red[0][tid] + red[0][tid+64] + red[0][tid+128] + red[0][tid+192];
        float QW = red[1][tid] + red[1][tid+64] + red[1][tid+128] + red[1][tid+192];
        QW += attn_ob[v*512 + ec*64 + tid];
        float pj = proj_w[v*512 + ec*64 + tid];
        float pc1 = wave_sum(PW*pj);
        float pc0 = wave_sum(QW*pj);
        if (tid == 0) {
            parts[v*8 + ec]      = pc1;
            parts[16 + v*8 + ec] = pc0;
        }
    }
}

__global__ void consts_final_k(const float* __restrict__ parts,
                               const float* __restrict__ proj_b,
                               float* __restrict__ consts)
{
    int tid = threadIdx.x;
    if (tid < 2) {
        float s1 = 0.f, s0 = 0.f;
        for (int c = 0; c < 8; ++c) { s1 += parts[tid*8 + c]; s0 += parts[16 + tid*8 + c]; }
        const float inv = 0.044194173824159216f; // 1/sqrt(512)
        consts[tid]     = s1*inv;
        consts[2 + tid] = s0*inv + proj_b[tid];
    }
}

// ---------------- a_map = LN(relu(a_n @ a0_w + a0_b)) ----------------
__global__ __launch_bounds__(256) void a_map_k(
    const float* __restrict__ a_n, const float* __restrict__ a0_w,
    const float* __restrict__ a0_b, const float* __restrict__ g,
    const float* __restrict__ bta, float* __restrict__ amap)
{
    const int v = blockIdx.y;
    const int w = threadIdx.x >> 6, lane = threadIdx.x & 63;
    const int b = blockIdx.x*4 + w;
    __shared__ float arow[4][64];
    arow[w][lane] = a_n[((long)b*2 + v)*64 + lane];
    __syncthreads();
    float acc = a0_b[v*64 + lane];
    #pragma unroll 8
    for (int rp = 0; rp < 64; ++rp)
        acc = fmaf(arow[w][rp], a0_w[((long)v*64 + rp)*64 + lane], acc);
    float x = fmaxf(acc, 0.0f);
    float mu = wave_sum(x) * (1.0f/64.0f);
    float d = x - mu;
    float var = wave_sum(d*d) * (1.0f/64.0f);
    float y = d * rsqrtf(var + 1e-5f) * g[v*64 + lane] + bta[v*64 + lane];
    amap[((long)v*512 + b)*64 + lane] = y;
}

// ---------------- o = h2@w3 + b3; ffn_update = LN(o+amap); a_next = amap*(1+c1)+c0+alpha*u ----------------
__global__ __launch_bounds__(256) void ofuse_k(
    const float* __restrict__ h2, const float* __restrict__ w3,
    const float* __restrict__ b3, const float* __restrict__ lng,
    const float* __restrict__ lnb, const float* __restrict__ amap,
    const float* __restrict__ consts, const float* __restrict__ alpha,
    float* __restrict__ anext)
{
    const int v = blockIdx.y;
    const int w = threadIdx.x >> 6, lane = threadIdx.x & 63;
    const int b = blockIdx.x*4 + w;
    __shared__ float hrow[4][512];
    const float* h2p = h2 + ((long)v*512 + b)*512;
    #pragma unroll
    for (int i = 0; i < 8; ++i) hrow[w][lane + i*64] = h2p[lane + i*64];
    __syncthreads();
    float acc = b3[v*64 + lane];
    const float* w3p = w3 + (long)v*512*64 + lane;
    #pragma unroll 8
    for (int d = 0; d < 512; ++d)
        acc = fmaf(hrow[w][d], w3p[(long)d*64], acc);
    const float am = amap[((long)v*512 + b)*64 + lane];
    float t = acc + am;
    float mu = wave_sum(t) * (1.0f/64.0f);
    float dd = t - mu;
    float var = wave_sum(dd*dd) * (1.0f/64.0f);
    float u = dd * rsqrtf(var + 1e-5f) * lng[v*64+lane] + lnb[v*64+lane];
    float c1 = consts[v], c0 = consts[2+v];
    anext[((long)v*512 + b)*64 + lane] = am*(1.0f + c1) + c0 + alpha[v]*u;
}

extern "C" void kernel_launch(void* const* d_in, const int* in_sizes, int n_in,
                              void* d_out, int out_size, void* d_ws, size_t ws_size,
                              hipStream_t stream)
{
    const float* a_n      = (const float*)d_in[0];
    const float* BC       = (const float*)d_in[1];
    const float* Phi      = (const float*)d_in[2];
    const float* Wq_w     = (const float*)d_in[3];
    const float* Wq_b     = (const float*)d_in[4];
    const float* Wk_w     = (const float*)d_in[5];
    const float* Wk_b     = (const float*)d_in[6];
    const float* Wv_w     = (const float*)d_in[7];
    const float* Wv_b     = (const float*)d_in[8];
    const float* attn_ow  = (const float*)d_in[9];
    const float* attn_ob  = (const float*)d_in[10];
    const float* proj_w   = (const float*)d_in[11];
    const float* proj_b   = (const float*)d_in[12];
    const float* ffn_w1   = (const float*)d_in[13];
    const float* ffn_b1   = (const float*)d_in[14];
    const float* ffn_w2   = (const float*)d_in[15];
    const float* ffn_b2   = (const float*)d_in[16];
    const float* ffn_w3   = (const float*)d_in[17];
    const float* ffn_b3   = (const float*)d_in[18];
    const float* ffn_ln_g = (const float*)d_in[19];
    const float* ffn_ln_b = (const float*)d_in[20];
    const float* a0_w     = (const float*)d_in[21];
    const float* a0_b     = (const float*)d_in[22];
    const float* a0_ln_g  = (const float*)d_in[23];
    const float* a0_ln_b  = (const float*)d_in[24];
    const float* alpha    = (const float*)d_in[25];
    const float* sb_w     = (const float*)d_in[26];
    const float* sb_b     = (const float*)d_in[27];
    const float* cm_w1    = (const float*)d_in[28];
    const float* cm_b1    = (const float*)d_in[29];
    const float* cm_w2    = (const float*)d_in[30];
    const float* cm_b2    = (const float*)d_in[31];
    const float* fu_w1    = (const float*)d_in[32];
    const float* fu_b1    = (const float*)d_in[33];
    const float* fu_w2    = (const float*)d_in[34];
    const float* fu_b2    = (const float*)d_in[35];
    const float* fu_w3    = (const float*)d_in[36];
    const float* fu_b3    = (const float*)d_in[37];
    const float* fu_w4    = (const float*)d_in[38];
    const float* fu_b4    = (const float*)d_in[39];

    float* ws = (float*)d_ws;
    float* Kws    = ws + 0;        // 65536  [v][r][d]
    float* Vws    = ws + 65536;    // 65536
    float* KV     = ws + 131072;   // 65536  [v][h][k][l]
    float* parts  = ws + 196608;   // 32
    float* consts = ws + 196672;   // 4: c1[2], c0[2]
    float* amap   = ws + 196736;   // 65536  [v][b][r]
    float* anext  = ws + 262272;   // 65536
    float* h1     = ws + 327808;   // 524288 [v][b][d]
    float* h2     = ws + 852096;   // 524288
    float* fbuf   = ws + 1376384;  // 196608 [b][384]
    float* hA     = ws + 1572992;  // 131072 [b][256]
    float* hB     = ws + 1704064;  // 262144 [b][512]
    float* hC     = ws + 1966208;  // 131072 [b][256]
    float* UB     = ws + 2097280;  // 1048576 [b][v*1024+n]
    float* out    = (float*)d_out;

    // ---- control / fusion MLP chain ----
    control_k<<<512, 256, 0, stream>>>(BC, sb_w, sb_b, cm_w1, cm_b1, cm_w2, cm_b2, fbuf);
    gemm_k<false,1><<<dim3(4,8,1),256,0,stream>>>(fbuf, fu_w1, fu_b1, nullptr, hA,
        512,256,384, 384,256,256,0, 0,0,0,0,0);
    gemm_k<false,1><<<dim3(8,8,1),256,0,stream>>>(hA, fu_w2, fu_b2, nullptr, hB,
        512,512,256, 256,512,512,0, 0,0,0,0,0);
    gemm_k<false,1><<<dim3(4,8,1),256,0,stream>>>(hB, fu_w3, fu_b3, nullptr, hC,
        512,256,512, 512,256,256,0, 0,0,0,0,0);
    gemm_k<false,0><<<dim3(32,8,1),256,0,stream>>>(hC, fu_w4, fu_b4, nullptr, UB,
        512,2048,256, 256,2048,2048,0, 0,0,0,0,0);

    // ---- attention constants (batch-independent) ----
    kv_pre_k<<<dim3(8,4,4),256,0,stream>>>(Phi, Wk_w, Wk_b, Wv_w, Wv_b, Kws, Vws);
    kv_outer_k<<<16,256,0,stream>>>(Kws, Vws, KV);
    attn_parts_k<<<dim3(2,8),256,0,stream>>>(KV, Wq_w, Wq_b, attn_ow, attn_ob, proj_w, parts);
    consts_final_k<<<1,64,0,stream>>>(parts, proj_b, consts);

    // ---- per-(b,v) chain ----
    a_map_k<<<dim3(128,2),256,0,stream>>>(a_n, a0_w, a0_b, a0_ln_g, a0_ln_b, amap);
    gemm_k<false,1><<<dim3(8,8,2),256,0,stream>>>(amap, ffn_w1, ffn_b1, nullptr, h1,
        512,512,64, 64,512,512,0, 32768,32768,512,0,262144);
    gemm_k<false,1><<<dim3(8,8,2),256,0,stream>>>(h1, ffn_w2, ffn_b2, nullptr, h2,
        512,512,512, 512,512,512,0, 262144,262144,512,0,262144);
    ofuse_k<<<dim3(128,2),256,0,stream>>>(h2, ffn_w3, ffn_b3, ffn_ln_g, ffn_ln_b,
        amap, consts, alpha, anext);

    // ---- U_hat = a_next @ Phi^T + U_B  (writes d_out directly) ----
    gemm_k<true,2><<<dim3(16,8,2),256,0,stream>>>(anext, Phi, nullptr, UB, out,
        512,1024,64, 64,64,2048,2048, 32768,65536,0,1024,1024);
}

// Round 2
// 263.407 us; speedup vs baseline: 1.2317x; 1.2317x over previous
//
#include <hip/hip_runtime.h>
#include <hip/hip_bf16.h>
#include <math.h>

// Shapes (fixed)
// B=512, V=2, NX=1024, R=64, D=512, H=8, S=4, NC=2, HS=64, FIN=384

__device__ __forceinline__ float gelu_f(float x) {
    float x3 = x*x*x;
    return 0.5f*x*(1.0f + tanhf(0.7978845608028654f*(x + 0.044715f*x3)));
}

__device__ __forceinline__ float wave_sum(float x) {
    #pragma unroll
    for (int m = 32; m >= 1; m >>= 1) x += __shfl_xor(x, m, 64);
    return x;
}

// ---------------- generic tiled GEMM ----------------
// C[m,n] = epi( sum_k A[m,k]*B[k,n] + bias[n] )
// BTRANS: B stored N x K (ldb = row stride of N)
// EPI: 0 = +bias, 1 = gelu(+bias), 2 = +Add[m,n] (no bias)
template<bool BTRANS, int EPI>
__global__ __launch_bounds__(256) void gemm_k(
    const float* __restrict__ A, const float* __restrict__ B,
    const float* __restrict__ bias, const float* __restrict__ Add,
    float* __restrict__ C,
    int M, int N, int K, int lda, int ldb, int ldc, int ldadd,
    long aBS, long bBS, long biasBS, long addBS, long cBS)
{
    const int v = blockIdx.z;
    A += (long)v*aBS; B += (long)v*bBS; C += (long)v*cBS;
    if (bias) bias += (long)v*biasBS;
    if (Add)  Add  += (long)v*addBS;
    const int n0 = blockIdx.x*64, m0 = blockIdx.y*64;
    __shared__ float As[16][65];
    __shared__ float Bs[16][65];
    const int tid = threadIdx.x;
    const int tx = tid & 15, ty = tid >> 4;
    float acc[4][4] = {};
    for (int k0 = 0; k0 < K; k0 += 16) {
        {
            int kk = tid & 15, mm = tid >> 4;
            #pragma unroll
            for (int p = 0; p < 4; ++p)
                As[kk][mm + p*16] = A[(long)(m0 + mm + p*16)*lda + k0 + kk];
        }
        if (BTRANS) {
            int kk = tid & 15, nn = tid >> 4;
            #pragma unroll
            for (int p = 0; p < 4; ++p)
                Bs[kk][nn + p*16] = B[(long)(n0 + nn + p*16)*ldb + k0 + kk];
        } else {
            int nn = tid & 63, kk = tid >> 6;
            #pragma unroll
            for (int p = 0; p < 4; ++p)
                Bs[kk + p*4][nn] = B[(long)(k0 + kk + p*4)*ldb + n0 + nn];
        }
        __syncthreads();
        #pragma unroll
        for (int k = 0; k < 16; ++k) {
            float a[4], b[4];
            #pragma unroll
            for (int i = 0; i < 4; ++i) a[i] = As[k][ty*4+i];
            #pragma unroll
            for (int j = 0; j < 4; ++j) b[j] = Bs[k][tx*4+j];
            #pragma unroll
            for (int i = 0; i < 4; ++i)
                #pragma unroll
                for (int j = 0; j < 4; ++j)
                    acc[i][j] = fmaf(a[i], b[j], acc[i][j]);
        }
        __syncthreads();
    }
    #pragma unroll
    for (int i = 0; i < 4; ++i) {
        const int m = m0 + ty*4 + i;
        #pragma unroll
        for (int j = 0; j < 4; ++j) {
            const int n = n0 + tx*4 + j;
            float x = acc[i][j];
            if (EPI != 2) { if (bias) x += bias[n]; }
            if (EPI == 1) x = gelu_f(x);
            if (EPI == 2) x += Add[(long)m*ldadd + n];
            C[(long)m*ldc + n] = x;
        }
    }
}

// ---------------- control path: f = [sf(256), cf(128)] ----------------
__global__ __launch_bounds__(256) void control_k(
    const float* __restrict__ BC, const float* __restrict__ sb_w,
    const float* __restrict__ sb_b, const float* __restrict__ cm_w1,
    const float* __restrict__ cm_b1, const float* __restrict__ cm_w2,
    const float* __restrict__ cm_b2, float* __restrict__ f)
{
    const int b = blockIdx.x;
    const int tid = threadIdx.x;
    __shared__ float bc[6];
    __shared__ float cf1[64];
    if (tid < 6) bc[tid] = BC[b*6 + tid];
    __syncthreads();
    {
        int s = tid >> 6;
        f[(long)b*384 + tid] = gelu_f(bc[s]*sb_w[tid] + sb_b[tid]);
    }
    if (tid < 64) {
        cf1[tid] = gelu_f(bc[4]*cm_w1[tid] + bc[5]*cm_w1[64+tid] + cm_b1[tid]);
    }
    __syncthreads();
    if (tid < 128) {
        float acc = cm_b2[tid];
        #pragma unroll 8
        for (int i = 0; i < 64; ++i) acc = fmaf(cf1[i], cm_w2[i*128 + tid], acc);
        f[(long)b*384 + 256 + tid] = gelu_f(acc);
    }
}

// ---------------- K/V precompute (split-K GEMM): part[s][z][r][d] ----------------
// K[v,r,d] = sum_n Phi[v,n,r]*W[v,n,d]; z = v*2+which; n split into 8 chunks of 128
__global__ __launch_bounds__(256) void kv_part_k(
    const float* __restrict__ Phi,
    const float* __restrict__ Wkw, const float* __restrict__ Wvw,
    float* __restrict__ part)
{
    const int z = blockIdx.z;            // 0..3
    const int v = z >> 1;
    const float* W = (z & 1) ? Wvw : Wkw;
    const int s = blockIdx.y;            // n-chunk 0..7
    const int d0 = blockIdx.x * 64;
    const int n0 = s * 128;
    __shared__ float Ps[16][65];
    __shared__ float Ws[16][65];
    const int tid = threadIdx.x;
    const int tx = tid & 15, ty = tid >> 4;
    const float* Pbase = Phi + (long)v*1024*64;
    const float* Wbase = W   + (long)v*1024*512;
    float acc[4][4] = {};
    for (int k0 = 0; k0 < 128; k0 += 16) {
        const int cc = tid & 63, kk = tid >> 6;
        #pragma unroll
        for (int p = 0; p < 4; ++p) {
            Ps[kk + p*4][cc] = Pbase[(long)(n0 + k0 + kk + p*4)*64  + cc];
            Ws[kk + p*4][cc] = Wbase[(long)(n0 + k0 + kk + p*4)*512 + d0 + cc];
        }
        __syncthreads();
        #pragma unroll
        for (int k = 0; k < 16; ++k) {
            float a[4], b[4];
            #pragma unroll
            for (int i = 0; i < 4; ++i) a[i] = Ps[k][ty*4+i];
            #pragma unroll
            for (int j = 0; j < 4; ++j) b[j] = Ws[k][tx*4+j];
            #pragma unroll
            for (int i = 0; i < 4; ++i)
                #pragma unroll
                for (int j = 0; j < 4; ++j)
                    acc[i][j] = fmaf(a[i], b[j], acc[i][j]);
        }
        __syncthreads();
    }
    float* outp = part + (((long)s*4 + z)*64)*512 + d0;
    #pragma unroll
    for (int i = 0; i < 4; ++i)
        #pragma unroll
        for (int j = 0; j < 4; ++j)
            outp[(long)(ty*4+i)*512 + tx*4+j] = acc[i][j];
}

// reduce partials + bias -> Kws/Vws  [v][r][d]
__global__ __launch_bounds__(256) void kv_reduce_k(
    const float* __restrict__ part,
    const float* __restrict__ Wkb, const float* __restrict__ Wvb,
    float* __restrict__ Kws, float* __restrict__ Vws)
{
    const long i = (long)blockIdx.x*256 + threadIdx.x;   // over 4*64*512
    float s = 0.f;
    #pragma unroll
    for (int ss = 0; ss < 8; ++ss) s += part[(long)ss*131072 + i];
    const int z = (int)(i >> 15);
    const int v = z >> 1;
    const int d = (int)(i & 511);
    s += ((z & 1) ? Wvb : Wkb)[v*512 + d];
    float* C = (z & 1) ? Vws : Kws;
    C[(long)v*32768 + (i & 32767)] = s;
}

// ---------------- KV[v,h,k,l] = sum_r K[v,r,h*64+k]*V[v,r,h*64+l] ----------------
__global__ __launch_bounds__(256) void kv_outer_k(
    const float* __restrict__ Kws, const float* __restrict__ Vws,
    float* __restrict__ KV)
{
    const int z = blockIdx.x;
    const int v = z >> 3, h = z & 7;
    __shared__ float Ks[64][64];
    __shared__ float Vs[64][64];
    const int tid = threadIdx.x;
    for (int idx = tid; idx < 4096; idx += 256) {
        int r = idx >> 6, c = idx & 63;
        long off = ((long)v*64 + r)*512 + h*64 + c;
        Ks[r][c] = Kws[off];
        Vs[r][c] = Vws[off];
    }
    __syncthreads();
    const int tx = tid & 15, ty = tid >> 4;
    float acc[4][4] = {};
    #pragma unroll 4
    for (int r = 0; r < 64; ++r) {
        float a[4], bb[4];
        #pragma unroll
        for (int i = 0; i < 4; ++i) a[i] = Ks[r][ty*4+i];
        #pragma unroll
        for (int j = 0; j < 4; ++j) bb[j] = Vs[r][tx*4+j];
        #pragma unroll
        for (int i = 0; i < 4; ++i)
            #pragma unroll
            for (int j = 0; j < 4; ++j)
                acc[i][j] = fmaf(a[i], bb[j], acc[i][j]);
    }
    #pragma unroll
    for (int i = 0; i < 4; ++i)
        #pragma unroll
        for (int j = 0; j < 4; ++j)
            KV[(((long)v*8 + h)*64 + ty*4+i)*64 + tx*4+j] = acc[i][j];
}

// ---------------- attention constants: partial reductions over e-chunks ----------------
__global__ __launch_bounds__(256) void attn_parts_k(
    const float* __restrict__ KV, const float* __restrict__ Wq_w,
    const float* __restrict__ Wq_b, const float* __restrict__ attn_ow,
    const float* __restrict__ attn_ob, const float* __restrict__ proj_w,
    float* __restrict__ parts)
{
    const int v = blockIdx.x;
    const int ec = blockIdx.y;   // e-chunk of 64
    const int tid = threadIdx.x;
    __shared__ float Pv[512];
    __shared__ float Qv[512];
    // phase 1: Pvec/Qvec (cheap, recomputed per block)
    for (int dp = tid; dp < 512; dp += 256) {
        int h = dp >> 6, l = dp & 63;
        const float* kvp = KV + ((long)(v*8 + h)*64)*64 + l;
        const float* wq = Wq_w + v*512 + h*64;
        const float* wb = Wq_b + v*512 + h*64;
        float p = 0.f, q = 0.f;
        #pragma unroll 8
        for (int k = 0; k < 64; ++k) {
            float kv = kvp[(long)k*64];
            p = fmaf(wq[k], kv, p);
            q = fmaf(wb[k], kv, q);
        }
        Pv[dp] = p; Qv[dp] = q;
    }
    __syncthreads();
    // phase 2: Pw/Qw for 64 e's, then dot with proj_w
    const int e = ec*64 + (tid & 63);
    const int qd = tid >> 6;
    float pw = 0.f, qw = 0.f;
    const float* owp = attn_ow + (long)v*512*512 + e;
    #pragma unroll 8
    for (int d = qd*128; d < qd*128 + 128; ++d) {
        float wv = owp[(long)d*512];
        pw = fmaf(Pv[d], wv, pw);
        qw = fmaf(Qv[d], wv, qw);
    }
    __shared__ float red[2][256];
    red[0][tid] = pw; red[1][tid] = qw;
    __syncthreads();
    if (tid < 64) {
        float PW = red[0][tid] + red[0][tid+64] + red[0][tid+128] + red[0][tid+192];
        float QW = red[1][tid] + red[1][tid+64] + red[1][tid+128] + red[1][tid+192];
        QW += attn_ob[v*512 + ec*64 + tid];
        float pj = proj_w[v*512 + ec*64 + tid];
        float pc1 = wave_sum(PW*pj);
        float pc0 = wave_sum(QW*pj);
        if (tid == 0) {
            parts[v*8 + ec]      = pc1;
            parts[16 + v*8 + ec] = pc0;
        }
    }
}

__global__ void consts_final_k(const float* __restrict__ parts,
                               const float* __restrict__ proj_b,
                               float* __restrict__ consts)
{
    int tid = threadIdx.x;
    if (tid < 2) {
        float s1 = 0.f, s0 = 0.f;
        for (int c = 0; c < 8; ++c) { s1 += parts[tid*8 + c]; s0 += parts[16 + tid*8 + c]; }
        const float inv = 0.044194173824159216f; // 1/sqrt(512)
        consts[tid]     = s1*inv;
        consts[2 + tid] = s0*inv + proj_b[tid];
    }
}

// ---------------- a_map = LN(relu(a_n @ a0_w + a0_b)) ----------------
__global__ __launch_bounds__(256) void a_map_k(
    const float* __restrict__ a_n, const float* __restrict__ a0_w,
    const float* __restrict__ a0_b, const float* __restrict__ g,
    const float* __restrict__ bta, float* __restrict__ amap)
{
    const int v = blockIdx.y;
    const int w = threadIdx.x >> 6, lane = threadIdx.x & 63;
    const int b = blockIdx.x*4 + w;
    __shared__ float arow[4][64];
    arow[w][lane] = a_n[((long)b*2 + v)*64 + lane];
    __syncthreads();
    float acc = a0_b[v*64 + lane];
    #pragma unroll 8
    for (int rp = 0; rp < 64; ++rp)
        acc = fmaf(arow[w][rp], a0_w[((long)v*64 + rp)*64 + lane], acc);
    float x = fmaxf(acc, 0.0f);
    float mu = wave_sum(x) * (1.0f/64.0f);
    float d = x - mu;
    float var = wave_sum(d*d) * (1.0f/64.0f);
    float y = d * rsqrtf(var + 1e-5f) * g[v*64 + lane] + bta[v*64 + lane];
    amap[((long)v*512 + b)*64 + lane] = y;
}

// ---------------- o = h2@w3 + b3; ffn_update = LN(o+amap); a_next = amap*(1+c1)+c0+alpha*u ----------------
__global__ __launch_bounds__(256) void ofuse_k(
    const float* __restrict__ h2, const float* __restrict__ w3,
    const float* __restrict__ b3, const float* __restrict__ lng,
    const float* __restrict__ lnb, const float* __restrict__ amap,
    const float* __restrict__ consts, const float* __restrict__ alpha,
    float* __restrict__ anext)
{
    const int v = blockIdx.y;
    const int w = threadIdx.x >> 6, lane = threadIdx.x & 63;
    const int b = blockIdx.x*4 + w;
    __shared__ float hrow[4][512];
    const float* h2p = h2 + ((long)v*512 + b)*512;
    #pragma unroll
    for (int i = 0; i < 8; ++i) hrow[w][lane + i*64] = h2p[lane + i*64];
    __syncthreads();
    float acc = b3[v*64 + lane];
    const float* w3p = w3 + (long)v*512*64 + lane;
    #pragma unroll 8
    for (int d = 0; d < 512; ++d)
        acc = fmaf(hrow[w][d], w3p[(long)d*64], acc);
    const float am = amap[((long)v*512 + b)*64 + lane];
    float t = acc + am;
    float mu = wave_sum(t) * (1.0f/64.0f);
    float dd = t - mu;
    float var = wave_sum(dd*dd) * (1.0f/64.0f);
    float u = dd * rsqrtf(var + 1e-5f) * lng[v*64+lane] + lnb[v*64+lane];
    float c1 = consts[v], c0 = consts[2+v];
    anext[((long)v*512 + b)*64 + lane] = am*(1.0f + c1) + c0 + alpha[v]*u;
}

extern "C" void kernel_launch(void* const* d_in, const int* in_sizes, int n_in,
                              void* d_out, int out_size, void* d_ws, size_t ws_size,
                              hipStream_t stream)
{
    const float* a_n      = (const float*)d_in[0];
    const float* BC       = (const float*)d_in[1];
    const float* Phi      = (const float*)d_in[2];
    const float* Wq_w     = (const float*)d_in[3];
    const float* Wq_b     = (const float*)d_in[4];
    const float* Wk_w     = (const float*)d_in[5];
    const float* Wk_b     = (const float*)d_in[6];
    const float* Wv_w     = (const float*)d_in[7];
    const float* Wv_b     = (const float*)d_in[8];
    const float* attn_ow  = (const float*)d_in[9];
    const float* attn_ob  = (const float*)d_in[10];
    const float* proj_w   = (const float*)d_in[11];
    const float* proj_b   = (const float*)d_in[12];
    const float* ffn_w1   = (const float*)d_in[13];
    const float* ffn_b1   = (const float*)d_in[14];
    const float* ffn_w2   = (const float*)d_in[15];
    const float* ffn_b2   = (const float*)d_in[16];
    const float* ffn_w3   = (const float*)d_in[17];
    const float* ffn_b3   = (const float*)d_in[18];
    const float* ffn_ln_g = (const float*)d_in[19];
    const float* ffn_ln_b = (const float*)d_in[20];
    const float* a0_w     = (const float*)d_in[21];
    const float* a0_b     = (const float*)d_in[22];
    const float* a0_ln_g  = (const float*)d_in[23];
    const float* a0_ln_b  = (const float*)d_in[24];
    const float* alpha    = (const float*)d_in[25];
    const float* sb_w     = (const float*)d_in[26];
    const float* sb_b     = (const float*)d_in[27];
    const float* cm_w1    = (const float*)d_in[28];
    const float* cm_b1    = (const float*)d_in[29];
    const float* cm_w2    = (const float*)d_in[30];
    const float* cm_b2    = (const float*)d_in[31];
    const float* fu_w1    = (const float*)d_in[32];
    const float* fu_b1    = (const float*)d_in[33];
    const float* fu_w2    = (const float*)d_in[34];
    const float* fu_b2    = (const float*)d_in[35];
    const float* fu_w3    = (const float*)d_in[36];
    const float* fu_b3    = (const float*)d_in[37];
    const float* fu_w4    = (const float*)d_in[38];
    const float* fu_b4    = (const float*)d_in[39];

    float* ws = (float*)d_ws;
    float* Kws    = ws + 0;        // 65536  [v][r][d]
    float* Vws    = ws + 65536;    // 65536
    float* KV     = ws + 131072;   // 65536  [v][h][k][l]
    float* parts  = ws + 196608;   // 32
    float* consts = ws + 196672;   // 4: c1[2], c0[2]
    float* amap   = ws + 196736;   // 65536  [v][b][r]
    float* anext  = ws + 262272;   // 65536
    float* h1     = ws + 327808;   // 524288 [v][b][d]
    float* h2     = ws + 852096;   // 524288
    float* fbuf   = ws + 1376384;  // 196608 [b][384]
    float* hA     = ws + 1572992;  // 131072 [b][256]
    float* hB     = ws + 1704064;  // 262144 [b][512]
    float* hC     = ws + 1966208;  // 131072 [b][256]
    float* UB     = ws + 2097280;  // 1048576 [b][v*1024+n]
    float* kvpart = h1;            // aliases h1+h2 (1048576 floats); consumed
                                   // by kv_reduce_k before ffn1 writes h1
    float* out    = (float*)d_out;

    // ---- K/V precompute (split-K) ----
    kv_part_k<<<dim3(8,8,4),256,0,stream>>>(Phi, Wk_w, Wv_w, kvpart);
    kv_reduce_k<<<512,256,0,stream>>>(kvpart, Wk_b, Wv_b, Kws, Vws);
    kv_outer_k<<<16,256,0,stream>>>(Kws, Vws, KV);
    attn_parts_k<<<dim3(2,8),256,0,stream>>>(KV, Wq_w, Wq_b, attn_ow, attn_ob, proj_w, parts);
    consts_final_k<<<1,64,0,stream>>>(parts, proj_b, consts);

    // ---- control / fusion MLP chain ----
    control_k<<<512, 256, 0, stream>>>(BC, sb_w, sb_b, cm_w1, cm_b1, cm_w2, cm_b2, fbuf);
    gemm_k<false,1><<<dim3(4,8,1),256,0,stream>>>(fbuf, fu_w1, fu_b1, nullptr, hA,
        512,256,384, 384,256,256,0, 0,0,0,0,0);
    gemm_k<false,1><<<dim3(8,8,1),256,0,stream>>>(hA, fu_w2, fu_b2, nullptr, hB,
        512,512,256, 256,512,512,0, 0,0,0,0,0);
    gemm_k<false,1><<<dim3(4,8,1),256,0,stream>>>(hB, fu_w3, fu_b3, nullptr, hC,
        512,256,512, 512,256,256,0, 0,0,0,0,0);
    gemm_k<false,0><<<dim3(32,8,1),256,0,stream>>>(hC, fu_w4, fu_b4, nullptr, UB,
        512,2048,256, 256,2048,2048,0, 0,0,0,0,0);

    // ---- per-(b,v) chain ----
    a_map_k<<<dim3(128,2),256,0,stream>>>(a_n, a0_w, a0_b, a0_ln_g, a0_ln_b, amap);
    gemm_k<false,1><<<dim3(8,8,2),256,0,stream>>>(amap, ffn_w1, ffn_b1, nullptr, h1,
        512,512,64, 64,512,512,0, 32768,32768,512,0,262144);
    gemm_k<false,1><<<dim3(8,8,2),256,0,stream>>>(h1, ffn_w2, ffn_b2, nullptr, h2,
        512,512,512, 512,512,512,0, 262144,262144,512,0,262144);
    ofuse_k<<<dim3(128,2),256,0,stream>>>(h2, ffn_w3, ffn_b3, ffn_ln_g, ffn_ln_b,
        amap, consts, alpha, anext);

    // ---- U_hat = a_next @ Phi^T + U_B  (writes d_out directly) ----
    gemm_k<true,2><<<dim3(16,8,2),256,0,stream>>>(anext, Phi, nullptr, UB, out,
        512,1024,64, 64,64,2048,2048, 32768,65536,0,1024,1024);
}

// Round 3
// 134.431 us; speedup vs baseline: 2.4135x; 1.9594x over previous
//
#include <hip/hip_runtime.h>
#include <hip/hip_bf16.h>
#include <math.h>

// Shapes (fixed): B=512, V=2, NX=1024, R=64, D=512, H=8, S=4, NC=2, HS=64, FIN=384

typedef unsigned short ushort_t;
using short8 = __attribute__((ext_vector_type(8))) short;
using f32x4  = __attribute__((ext_vector_type(4))) float;

__device__ __forceinline__ float gelu_f(float x) {
    float x3 = x*x*x;
    return 0.5f*x*(1.0f + tanhf(0.7978845608028654f*(x + 0.044715f*x3)));
}

__device__ __forceinline__ float wave_sum(float x) {
    #pragma unroll
    for (int m = 32; m >= 1; m >>= 1) x += __shfl_xor(x, m, 64);
    return x;
}

__device__ __forceinline__ ushort_t f2bf(float x) {
    unsigned u = __float_as_uint(x);
    unsigned r = (u + 0x7FFFu + ((u >> 16) & 1u)) >> 16;   // RNE
    return (ushort_t)r;
}
__device__ __forceinline__ float bf2f(ushort_t h) {
    return __uint_as_float(((unsigned)h) << 16);
}

// ---------------- weight convert / transpose (one launch, descriptor table) ----
struct CvtDesc { const float* src; ushort_t* dst; int K, N, flat; };
struct CvtArgs { CvtDesc d[15]; int cum[16]; };

__global__ __launch_bounds__(256) void cvt_k(CvtArgs a)
{
    const int bid = blockIdx.x, t = threadIdx.x;
    int e = 0;
    while (bid >= a.cum[e+1]) ++e;
    const CvtDesc d = a.d[e];
    const int tile = bid - a.cum[e];
    if (d.flat) {
        const long base = (long)tile*4096 + t*16;
        const float4* s = (const float4*)(d.src + base);
        ushort4* o = (ushort4*)(d.dst + base);
        #pragma unroll
        for (int i = 0; i < 4; ++i) {
            float4 v = s[i];
            ushort4 w; w.x=f2bf(v.x); w.y=f2bf(v.y); w.z=f2bf(v.z); w.w=f2bf(v.w);
            o[i] = w;
        }
    } else {
        // transpose fp32 [K][N] tile(32x32) -> bf16 [N][K]
        __shared__ float tl[32][33];
        const int ntn = d.N >> 5;
        const int kt = tile / ntn, nt = tile % ntn;
        const int r = t >> 3, c0 = (t & 7) * 4;
        float4 v = *(const float4*)(d.src + (long)(kt*32 + r)*d.N + nt*32 + c0);
        tl[r][c0] = v.x; tl[r][c0+1] = v.y; tl[r][c0+2] = v.z; tl[r][c0+3] = v.w;
        __syncthreads();
        ushort4 w;
        w.x = f2bf(tl[c0+0][r]); w.y = f2bf(tl[c0+1][r]);
        w.z = f2bf(tl[c0+2][r]); w.w = f2bf(tl[c0+3][r]);
        *(ushort4*)(d.dst + (long)(nt*32 + r)*d.K + kt*32 + c0) = w;
    }
}

// ---------------- bf16 MFMA GEMM ----------------
// C[m,n] = epi( sum_k A[m,k]*Bt[n,k] ), A bf16 [M][K], Bt bf16 [N][K].
// EPI: 0 = +bias, 1 = gelu(+bias), 2 = +Add (fp32 out, no bias)
// OUTBF: write bf16 (else fp32)
template<int EPI, bool OUTBF>
__global__ __launch_bounds__(256) void bgemm_k(
    const ushort_t* __restrict__ A, const ushort_t* __restrict__ B,
    const float* __restrict__ bias, const float* __restrict__ Add,
    void* __restrict__ Cv,
    int M, int N, int K, int ldc, int ldadd,
    long aBS, long bBS, long biasBS, long addBS, long cBS)
{
    const int v = blockIdx.z;
    A += (long)v*aBS; B += (long)v*bBS;
    if (EPI != 2) bias += (long)v*biasBS;
    const int n0 = blockIdx.x*64, m0 = blockIdx.y*64;
    __shared__ ushort_t lds[2][2][64][40];   // [buf][A/B][row][32 data + 8 pad]
    const int tid = threadIdx.x;
    const int w = tid >> 6, l = tid & 63;
    const int ml = l & 15, kg = l >> 4;
    const int srow = tid >> 2, sslot = tid & 3;
    const ushort_t* Ag = A + (long)(m0 + srow)*K + sslot*8;
    const ushort_t* Bg = B + (long)(n0 + srow)*K + sslot*8;
    f32x4 acc[4] = {};
    const int nt = K >> 5;
    int4 ra = *(const int4*)Ag;
    int4 rb = *(const int4*)Bg;
    *(int4*)&lds[0][0][srow][sslot*8] = ra;
    *(int4*)&lds[0][1][srow][sslot*8] = rb;
    __syncthreads();
    for (int t = 0; t < nt; ++t) {
        const int cur = t & 1;
        if (t + 1 < nt) {
            ra = *(const int4*)(Ag + (t+1)*32);
            rb = *(const int4*)(Bg + (t+1)*32);
        }
        short8 af = *(const short8*)&lds[cur][0][w*16 + ml][kg*8];
        #pragma unroll
        for (int f = 0; f < 4; ++f) {
            short8 bfr = *(const short8*)&lds[cur][1][f*16 + ml][kg*8];
            acc[f] = __builtin_amdgcn_mfma_f32_16x16x32_bf16(af, bfr, acc[f], 0, 0, 0);
        }
        if (t + 1 < nt) {
            *(int4*)&lds[cur^1][0][srow][sslot*8] = ra;
            *(int4*)&lds[cur^1][1][srow][sslot*8] = rb;
            __syncthreads();
        }
    }
    float* Cf = (float*)Cv; ushort_t* Cb = (ushort_t*)Cv;
    if (OUTBF) Cb += (long)v*cBS; else Cf += (long)v*cBS;
    if (EPI == 2) Add += (long)v*addBS;
    const int mr = m0 + w*16 + kg*4;
    const int nc = n0 + ml;
    #pragma unroll
    for (int f = 0; f < 4; ++f) {
        const int n = nc + f*16;
        const float bs = (EPI != 2) ? bias[n] : 0.0f;
        #pragma unroll
        for (int r = 0; r < 4; ++r) {
            float x = acc[f][r] + bs;
            if (EPI == 1) x = gelu_f(x);
            if (EPI == 2) x = acc[f][r] + Add[(long)(mr + r)*ldadd + n];
            if (OUTBF) Cb[(long)(mr + r)*ldc + n] = f2bf(x);
            else       Cf[(long)(mr + r)*ldc + n] = x;
        }
    }
}

// ---------------- control path: f = [sf(256), cf(128)] (bf16 out) ----------------
__global__ __launch_bounds__(256) void control_k(
    const float* __restrict__ BC, const float* __restrict__ sb_w,
    const float* __restrict__ sb_b, const float* __restrict__ cm_w1,
    const float* __restrict__ cm_b1, const float* __restrict__ cm_w2,
    const float* __restrict__ cm_b2, ushort_t* __restrict__ f)
{
    const int b = blockIdx.x;
    const int tid = threadIdx.x;
    __shared__ float bc[6];
    __shared__ float cf1[64];
    if (tid < 6) bc[tid] = BC[b*6 + tid];
    __syncthreads();
    {
        int s = tid >> 6;
        f[(long)b*384 + tid] = f2bf(gelu_f(bc[s]*sb_w[tid] + sb_b[tid]));
    }
    if (tid < 64) {
        cf1[tid] = gelu_f(bc[4]*cm_w1[tid] + bc[5]*cm_w1[64+tid] + cm_b1[tid]);
    }
    __syncthreads();
    if (tid < 128) {
        float acc = cm_b2[tid];
        #pragma unroll 8
        for (int i = 0; i < 64; ++i) acc = fmaf(cf1[i], cm_w2[i*128 + tid], acc);
        f[(long)b*384 + 256 + tid] = f2bf(gelu_f(acc));
    }
}

// ---------------- KV[v,h,k,l] = sum_r K[v,r,h*64+k]*V[v,r,h*64+l] ----------------
__global__ __launch_bounds__(256) void kv_outer_k(
    const float* __restrict__ Kws, const float* __restrict__ Vws,
    float* __restrict__ KV)
{
    const int z = blockIdx.x;
    const int v = z >> 3, h = z & 7;
    __shared__ float Ks[64][64];
    __shared__ float Vs[64][64];
    const int tid = threadIdx.x;
    for (int idx = tid; idx < 4096; idx += 256) {
        int r = idx >> 6, c = idx & 63;
        long off = ((long)v*64 + r)*512 + h*64 + c;
        Ks[r][c] = Kws[off];
        Vs[r][c] = Vws[off];
    }
    __syncthreads();
    const int tx = tid & 15, ty = tid >> 4;
    float acc[4][4] = {};
    #pragma unroll 4
    for (int r = 0; r < 64; ++r) {
        float a[4], bb[4];
        #pragma unroll
        for (int i = 0; i < 4; ++i) a[i] = Ks[r][ty*4+i];
        #pragma unroll
        for (int j = 0; j < 4; ++j) bb[j] = Vs[r][tx*4+j];
        #pragma unroll
        for (int i = 0; i < 4; ++i)
            #pragma unroll
            for (int j = 0; j < 4; ++j)
                acc[i][j] = fmaf(a[i], bb[j], acc[i][j]);
    }
    #pragma unroll
    for (int i = 0; i < 4; ++i)
        #pragma unroll
        for (int j = 0; j < 4; ++j)
            KV[(((long)v*8 + h)*64 + ty*4+i)*64 + tx*4+j] = acc[i][j];
}

// ---------------- attention constants ----------------
__global__ __launch_bounds__(256) void attn_parts_k(
    const float* __restrict__ KV, const float* __restrict__ Wq_w,
    const float* __restrict__ Wq_b, const float* __restrict__ attn_ow,
    const float* __restrict__ attn_ob, const float* __restrict__ proj_w,
    float* __restrict__ parts)
{
    const int v = blockIdx.x;
    const int ec = blockIdx.y;   // e-chunk of 64
    const int tid = threadIdx.x;
    __shared__ float Pv[512];
    __shared__ float Qv[512];
    for (int dp = tid; dp < 512; dp += 256) {
        int h = dp >> 6, l = dp & 63;
        const float* kvp = KV + ((long)(v*8 + h)*64)*64 + l;
        const float* wq = Wq_w + v*512 + h*64;
        const float* wb = Wq_b + v*512 + h*64;
        float p = 0.f, q = 0.f;
        #pragma unroll 8
        for (int k = 0; k < 64; ++k) {
            float kv = kvp[(long)k*64];
            p = fmaf(wq[k], kv, p);
            q = fmaf(wb[k], kv, q);
        }
        Pv[dp] = p; Qv[dp] = q;
    }
    __syncthreads();
    const int e = ec*64 + (tid & 63);
    const int qd = tid >> 6;
    float pw = 0.f, qw = 0.f;
    const float* owp = attn_ow + (long)v*512*512 + e;
    #pragma unroll 8
    for (int d = qd*128; d < qd*128 + 128; ++d) {
        float wv = owp[(long)d*512];
        pw = fmaf(Pv[d], wv, pw);
        qw = fmaf(Qv[d], wv, qw);
    }
    __shared__ float red[2][256];
    red[0][tid] = pw; red[1][tid] = qw;
    __syncthreads();
    if (tid < 64) {
        float PW = red[0][tid] + red[0][tid+64] + red[0][tid+128] + red[0][tid+192];
        float QW = red[1][tid] + red[1][tid+64] + red[1][tid+128] + red[1][tid+192];
        QW += attn_ob[v*512 + ec*64 + tid];
        float pj = proj_w[v*512 + ec*64 + tid];
        float pc1 = wave_sum(PW*pj);
        float pc0 = wave_sum(QW*pj);
        if (tid == 0) {
            parts[v*8 + ec]      = pc1;
            parts[16 + v*8 + ec] = pc0;
        }
    }
}

__global__ void consts_final_k(const float* __restrict__ parts,
                               const float* __restrict__ proj_b,
                               float* __restrict__ consts)
{
    int tid = threadIdx.x;
    if (tid < 2) {
        float s1 = 0.f, s0 = 0.f;
        for (int c = 0; c < 8; ++c) { s1 += parts[tid*8 + c]; s0 += parts[16 + tid*8 + c]; }
        const float inv = 0.044194173824159216f; // 1/sqrt(512)
        consts[tid]     = s1*inv;
        consts[2 + tid] = s0*inv + proj_b[tid];
    }
}

// ---------------- a_map = LN(relu(a_n @ a0_w + a0_b))  (bf16 out) ----------------
__global__ __launch_bounds__(256) void a_map_k(
    const float* __restrict__ a_n, const float* __restrict__ a0_w,
    const float* __restrict__ a0_b, const float* __restrict__ g,
    const float* __restrict__ bta, ushort_t* __restrict__ amap)
{
    const int v = blockIdx.y;
    const int w = threadIdx.x >> 6, lane = threadIdx.x & 63;
    const int b = blockIdx.x*4 + w;
    __shared__ float arow[4][64];
    arow[w][lane] = a_n[((long)b*2 + v)*64 + lane];
    __syncthreads();
    float acc = a0_b[v*64 + lane];
    #pragma unroll 8
    for (int rp = 0; rp < 64; ++rp)
        acc = fmaf(arow[w][rp], a0_w[((long)v*64 + rp)*64 + lane], acc);
    float x = fmaxf(acc, 0.0f);
    float mu = wave_sum(x) * (1.0f/64.0f);
    float d = x - mu;
    float var = wave_sum(d*d) * (1.0f/64.0f);
    float y = d * rsqrtf(var + 1e-5f) * g[v*64 + lane] + bta[v*64 + lane];
    amap[((long)v*512 + b)*64 + lane] = f2bf(y);
}

// ---------------- ofuse: o = h2@w3 + b3; u = LN(o+amap); a_next = amap*(1+c1)+c0+alpha*u ----
__global__ __launch_bounds__(256) void ofuse_k(
    const ushort_t* __restrict__ h2, const float* __restrict__ w3,
    const float* __restrict__ b3, const float* __restrict__ lng,
    const float* __restrict__ lnb, const ushort_t* __restrict__ amap,
    const float* __restrict__ consts, const float* __restrict__ alpha,
    ushort_t* __restrict__ anext)
{
    const int v = blockIdx.y;
    const int w = threadIdx.x >> 6, lane = threadIdx.x & 63;
    const int b = blockIdx.x*4 + w;
    __shared__ float hrow[4][512];
    const ushort_t* h2p = h2 + ((long)v*512 + b)*512;
    #pragma unroll
    for (int i = 0; i < 8; ++i) hrow[w][lane + i*64] = bf2f(h2p[lane + i*64]);
    __syncthreads();
    float acc = b3[v*64 + lane];
    const float* w3p = w3 + (long)v*512*64 + lane;
    #pragma unroll 8
    for (int d = 0; d < 512; ++d)
        acc = fmaf(hrow[w][d], w3p[(long)d*64], acc);
    const float am = bf2f(amap[((long)v*512 + b)*64 + lane]);
    float t = acc + am;
    float mu = wave_sum(t) * (1.0f/64.0f);
    float dd = t - mu;
    float var = wave_sum(dd*dd) * (1.0f/64.0f);
    float u = dd * rsqrtf(var + 1e-5f) * lng[v*64+lane] + lnb[v*64+lane];
    float c1 = consts[v], c0 = consts[2+v];
    anext[((long)v*512 + b)*64 + lane] = f2bf(am*(1.0f + c1) + c0 + alpha[v]*u);
}

extern "C" void kernel_launch(void* const* d_in, const int* in_sizes, int n_in,
                              void* d_out, int out_size, void* d_ws, size_t ws_size,
                              hipStream_t stream)
{
    const float* a_n      = (const float*)d_in[0];
    const float* BC       = (const float*)d_in[1];
    const float* Phi      = (const float*)d_in[2];
    const float* Wq_w     = (const float*)d_in[3];
    const float* Wq_b     = (const float*)d_in[4];
    const float* Wk_w     = (const float*)d_in[5];
    const float* Wk_b     = (const float*)d_in[6];
    const float* Wv_w     = (const float*)d_in[7];
    const float* Wv_b     = (const float*)d_in[8];
    const float* attn_ow  = (const float*)d_in[9];
    const float* attn_ob  = (const float*)d_in[10];
    const float* proj_w   = (const float*)d_in[11];
    const float* proj_b   = (const float*)d_in[12];
    const float* ffn_w1   = (const float*)d_in[13];
    const float* ffn_b1   = (const float*)d_in[14];
    const float* ffn_w2   = (const float*)d_in[15];
    const float* ffn_b2   = (const float*)d_in[16];
    const float* ffn_w3   = (const float*)d_in[17];
    const float* ffn_b3   = (const float*)d_in[18];
    const float* ffn_ln_g = (const float*)d_in[19];
    const float* ffn_ln_b = (const float*)d_in[20];
    const float* a0_w     = (const float*)d_in[21];
    const float* a0_b     = (const float*)d_in[22];
    const float* a0_ln_g  = (const float*)d_in[23];
    const float* a0_ln_b  = (const float*)d_in[24];
    const float* alpha    = (const float*)d_in[25];
    const float* sb_w     = (const float*)d_in[26];
    const float* sb_b     = (const float*)d_in[27];
    const float* cm_w1    = (const float*)d_in[28];
    const float* cm_b1    = (const float*)d_in[29];
    const float* cm_w2    = (const float*)d_in[30];
    const float* cm_b2    = (const float*)d_in[31];
    const float* fu_w1    = (const float*)d_in[32];
    const float* fu_b1    = (const float*)d_in[33];
    const float* fu_w2    = (const float*)d_in[34];
    const float* fu_b2    = (const float*)d_in[35];
    const float* fu_w3    = (const float*)d_in[36];
    const float* fu_b3    = (const float*)d_in[37];
    const float* fu_w4    = (const float*)d_in[38];
    const float* fu_b4    = (const float*)d_in[39];

    float* ws = (float*)d_ws;
    // ---- workspace layout (float units) ----
    float*   Kws      = ws;                              // 65536  [v][r][d] fp32
    float*   Vws      = ws + 65536;                      // 65536
    float*   KV       = ws + 131072;                     // 65536  [v][h][k][l]
    float*   parts    = ws + 196608;                     // 64
    float*   consts   = ws + 196672;                     // 64
    ushort_t* amap_bf  = (ushort_t*)(ws + 196736);       // 65536 elems
    ushort_t* anext_bf = (ushort_t*)(ws + 229504);       // 65536 elems
    ushort_t* h1_bf    = (ushort_t*)(ws + 262272);       // 524288 elems
    ushort_t* h2_bf    = (ushort_t*)(ws + 524416);       // 524288 elems
    ushort_t* fbuf_bf  = (ushort_t*)(ws + 786560);       // 196608 elems
    ushort_t* hA_bf    = (ushort_t*)(ws + 884864);       // 131072 elems
    ushort_t* hB_bf    = (ushort_t*)(ws + 950400);       // 262144 elems
    ushort_t* hC_bf    = (ushort_t*)(ws + 1081472);      // 131072 elems
    ushort_t* w_fu1t   = (ushort_t*)(ws + 1147008);      // 98304  [256][384]
    ushort_t* w_fu2t   = (ushort_t*)(ws + 1196160);      // 131072 [512][256]
    ushort_t* w_fu3t   = (ushort_t*)(ws + 1261696);      // 131072 [256][512]
    ushort_t* w_fu4t   = (ushort_t*)(ws + 1327232);      // 524288 [2048][256]
    ushort_t* w_ffn1t  = (ushort_t*)(ws + 1589376);      // 65536  [v][512][64]
    ushort_t* w_ffn2t  = (ushort_t*)(ws + 1622144);      // 524288 [v][512][512]
    ushort_t* Phi_bf   = (ushort_t*)(ws + 1884288);      // 131072 [v][1024][64]
    float*   UB       = ws + 1949824;                    // 1048576 fp32 [512][2048]
    ushort_t* Wk_t     = (ushort_t*)UB;                  // alias: 1048576 elems [v][512][1024]
    ushort_t* Wv_t     = ((ushort_t*)UB) + 1048576;      // alias: 1048576 elems
    ushort_t* Phi_t    = (ushort_t*)(ws + 2998400);      // 131072 [v][64][1024]
    float*   out      = (float*)d_out;

    // ---- conversion descriptor table ----
    CvtArgs ca;
    auto set = [&](int i, const float* s, ushort_t* dst, int K, int N, int flat) {
        ca.d[i].src = s; ca.d[i].dst = dst; ca.d[i].K = K; ca.d[i].N = N; ca.d[i].flat = flat;
    };
    set(0,  fu_w1,          w_fu1t,          384, 256,  0);
    set(1,  fu_w2,          w_fu2t,          256, 512,  0);
    set(2,  fu_w3,          w_fu3t,          512, 256,  0);
    set(3,  fu_w4,          w_fu4t,          256, 2048, 0);
    set(4,  ffn_w1,         w_ffn1t,         64,  512,  0);
    set(5,  ffn_w1 + 32768, w_ffn1t + 32768, 64,  512,  0);
    set(6,  ffn_w2,         w_ffn2t,          512, 512, 0);
    set(7,  ffn_w2 + 262144, w_ffn2t + 262144, 512, 512, 0);
    set(8,  Phi,            Phi_bf,          131072, 0, 1);
    set(9,  Phi,            Phi_t,           1024, 64,  0);
    set(10, Phi + 65536,    Phi_t + 65536,   1024, 64,  0);
    set(11, Wk_w,           Wk_t,            1024, 512, 0);
    set(12, Wk_w + 524288,  Wk_t + 524288,   1024, 512, 0);
    set(13, Wv_w,           Wv_t,            1024, 512, 0);
    set(14, Wv_w + 524288,  Wv_t + 524288,   1024, 512, 0);
    const int tl[15] = {96,128,128,512,32,32,256,256,32,64,64,512,512,512,512};
    ca.cum[0] = 0;
    for (int i = 0; i < 15; ++i) ca.cum[i+1] = ca.cum[i] + tl[i];
    cvt_k<<<ca.cum[15], 256, 0, stream>>>(ca);   // 3648 blocks

    // ---- K/V precompute: Kws[v] = Phi[v]^T @ Wk_w[v] + Wk_b (M=64,N=512,K=1024) ----
    bgemm_k<0,false><<<dim3(8,1,2),256,0,stream>>>(Phi_t, Wk_t, Wk_b, nullptr, Kws,
        64,512,1024, 512,0, 65536,524288,512,0,32768);
    bgemm_k<0,false><<<dim3(8,1,2),256,0,stream>>>(Phi_t, Wv_t, Wv_b, nullptr, Vws,
        64,512,1024, 512,0, 65536,524288,512,0,32768);
    kv_outer_k<<<16,256,0,stream>>>(Kws, Vws, KV);
    attn_parts_k<<<dim3(2,8),256,0,stream>>>(KV, Wq_w, Wq_b, attn_ow, attn_ob, proj_w, parts);
    consts_final_k<<<1,64,0,stream>>>(parts, proj_b, consts);

    // ---- control / fusion MLP chain ----
    control_k<<<512, 256, 0, stream>>>(BC, sb_w, sb_b, cm_w1, cm_b1, cm_w2, cm_b2, fbuf_bf);
    bgemm_k<1,true><<<dim3(4,8,1),256,0,stream>>>(fbuf_bf, w_fu1t, fu_b1, nullptr, hA_bf,
        512,256,384, 256,0, 0,0,0,0,0);
    bgemm_k<1,true><<<dim3(8,8,1),256,0,stream>>>(hA_bf, w_fu2t, fu_b2, nullptr, hB_bf,
        512,512,256, 512,0, 0,0,0,0,0);
    bgemm_k<1,true><<<dim3(4,8,1),256,0,stream>>>(hB_bf, w_fu3t, fu_b3, nullptr, hC_bf,
        512,256,512, 256,0, 0,0,0,0,0);
    // fu4 overwrites UB region (Wk_t/Wv_t already consumed above)
    bgemm_k<0,false><<<dim3(32,8,1),256,0,stream>>>(hC_bf, w_fu4t, fu_b4, nullptr, UB,
        512,2048,256, 2048,0, 0,0,0,0,0);

    // ---- per-(b,v) chain ----
    a_map_k<<<dim3(128,2),256,0,stream>>>(a_n, a0_w, a0_b, a0_ln_g, a0_ln_b, amap_bf);
    bgemm_k<1,true><<<dim3(8,8,2),256,0,stream>>>(amap_bf, w_ffn1t, ffn_b1, nullptr, h1_bf,
        512,512,64, 512,0, 32768,32768,512,0,262144);
    bgemm_k<1,true><<<dim3(8,8,2),256,0,stream>>>(h1_bf, w_ffn2t, ffn_b2, nullptr, h2_bf,
        512,512,512, 512,0, 262144,262144,512,0,262144);
    ofuse_k<<<dim3(128,2),256,0,stream>>>(h2_bf, ffn_w3, ffn_b3, ffn_ln_g, ffn_ln_b,
        amap_bf, consts, alpha, anext_bf);

    // ---- U_hat = a_next @ Phi^T + U_B  (fp32 out) ----
    bgemm_k<2,false><<<dim3(16,8,2),256,0,stream>>>(anext_bf, Phi_bf, nullptr, UB, out,
        512,1024,64, 2048,2048, 32768,65536,0,1024,1024);
}

// Round 4
// 77.582 us; speedup vs baseline: 4.1821x; 1.7328x over previous
//
#include <hip/hip_runtime.h>
#include <hip/hip_bf16.h>
#include <math.h>

// Shapes (fixed): B=512, V=2, NX=1024, R=64, D=512, H=8, S=4, NC=2, HS=64, FIN=384

typedef unsigned short ushort_t;
using short8 = __attribute__((ext_vector_type(8))) short;
using f32x4  = __attribute__((ext_vector_type(4))) float;

__device__ __forceinline__ float gelu_f(float x) {
    float x3 = x*x*x;
    return 0.5f*x*(1.0f + tanhf(0.7978845608028654f*(x + 0.044715f*x3)));
}

__device__ __forceinline__ float wave_sum(float x) {
    #pragma unroll
    for (int m = 32; m >= 1; m >>= 1) x += __shfl_xor(x, m, 64);
    return x;
}

__device__ __forceinline__ ushort_t f2bf(float x) {
    unsigned u = __float_as_uint(x);
    unsigned r = (u + 0x7FFFu + ((u >> 16) & 1u)) >> 16;   // RNE
    return (ushort_t)r;
}
__device__ __forceinline__ float bf2f(ushort_t h) {
    return __uint_as_float(((unsigned)h) << 16);
}

// ---------------- pointer bundle ----------------
struct Ptrs {
    // inputs
    const float *a_n, *BC, *Wq_w, *Wq_b, *Wk_b, *Wv_b, *attn_ow, *attn_ob,
                *proj_w, *proj_b, *ffn_w3, *ffn_b3, *ffn_ln_g, *ffn_ln_b,
                *a0_w, *a0_b, *a0_ln_g, *a0_ln_b, *alpha,
                *sb_w, *sb_b, *cm_w1, *cm_b1, *cm_w2, *cm_b2,
                *fu_b1, *fu_b2, *fu_b3, *fu_b4, *ffn_b1, *ffn_b2;
    // workspace
    float *Kws, *Vws, *KV, *parts, *UB, *out;
    ushort_t *amap_bf, *anext_bf, *h1_bf, *h2_bf, *fbuf_bf, *hA_bf, *hB_bf, *hC_bf;
    ushort_t *w_fu1t, *w_fu2t, *w_fu3t, *w_fu4t, *w_ffn1t, *w_ffn2t,
             *Phi_bf, *Wk_t, *Wv_t, *Phi_t;
};

// ---------------- cvt descriptors ----------------
struct CvtDesc { const float* src; ushort_t* dst; int K, N, flat; };
struct CvtArgs { CvtDesc d[15]; int cum[16]; };

__device__ void cvt_dev(char* smem, int tile, const CvtDesc& d)
{
    const int t = threadIdx.x;
    if (d.flat) {
        const long base = (long)tile*4096 + t*16;
        const float4* s = (const float4*)(d.src + base);
        ushort4* o = (ushort4*)(d.dst + base);
        #pragma unroll
        for (int i = 0; i < 4; ++i) {
            float4 v = s[i];
            ushort4 w; w.x=f2bf(v.x); w.y=f2bf(v.y); w.z=f2bf(v.z); w.w=f2bf(v.w);
            o[i] = w;
        }
    } else {
        float* tl = (float*)smem;               // [32][33]
        const int ntn = d.N >> 5;
        const int kt = tile / ntn, nt = tile % ntn;
        const int r = t >> 3, c0 = (t & 7) * 4;
        float4 v = *(const float4*)(d.src + (long)(kt*32 + r)*d.N + nt*32 + c0);
        tl[r*33 + c0] = v.x; tl[r*33 + c0+1] = v.y;
        tl[r*33 + c0+2] = v.z; tl[r*33 + c0+3] = v.w;
        __syncthreads();
        ushort4 w;
        w.x = f2bf(tl[(c0+0)*33 + r]); w.y = f2bf(tl[(c0+1)*33 + r]);
        w.z = f2bf(tl[(c0+2)*33 + r]); w.w = f2bf(tl[(c0+3)*33 + r]);
        *(ushort4*)(d.dst + (long)(nt*32 + r)*d.K + kt*32 + c0) = w;
    }
}

// ---------------- bf16 MFMA GEMM (device) ----------------
// C[m,n] = epi( sum_k A[m,k]*Bt[n,k] ); A bf16 [M][K], Bt bf16 [N][K] (both row-major, k-contig)
// EPI: 0 = +bias, 1 = gelu(+bias), 2 = +Add (no bias). OUTBF: bf16 out else fp32.
__device__ void bgemm_dev(char* smem_,
    const ushort_t* __restrict__ A, const ushort_t* __restrict__ B,
    const float* __restrict__ bias, const float* __restrict__ Add,
    void* __restrict__ Cv, int m0, int n0, int K, int ldc, int ldadd,
    int EPI, bool OUTBF)
{
    ushort_t* lds = (ushort_t*)smem_;   // [2][2][64][40]
    const int tid = threadIdx.x;
    const int w = tid >> 6, l = tid & 63;
    const int ml = l & 15, kg = l >> 4;
    const int srow = tid >> 2, sslot = tid & 3;
    const ushort_t* Ag = A + (long)(m0 + srow)*K + sslot*8;
    const ushort_t* Bg = B + (long)(n0 + srow)*K + sslot*8;
    auto L = [&](int buf, int ab, int row, int col) {
        return lds + (((buf*2 + ab)*64 + row)*40 + col);
    };
    f32x4 acc[4] = {};
    const int nt = K >> 5;
    int4 ra = *(const int4*)Ag;
    int4 rb = *(const int4*)Bg;
    *(int4*)L(0,0,srow,sslot*8) = ra;
    *(int4*)L(0,1,srow,sslot*8) = rb;
    __syncthreads();
    for (int t = 0; t < nt; ++t) {
        const int cur = t & 1;
        if (t + 1 < nt) {
            ra = *(const int4*)(Ag + (t+1)*32);
            rb = *(const int4*)(Bg + (t+1)*32);
        }
        short8 af = *(const short8*)L(cur,0,w*16 + ml,kg*8);
        #pragma unroll
        for (int f = 0; f < 4; ++f) {
            short8 bfr = *(const short8*)L(cur,1,f*16 + ml,kg*8);
            acc[f] = __builtin_amdgcn_mfma_f32_16x16x32_bf16(af, bfr, acc[f], 0, 0, 0);
        }
        if (t + 1 < nt) {
            *(int4*)L(cur^1,0,srow,sslot*8) = ra;
            *(int4*)L(cur^1,1,srow,sslot*8) = rb;
            __syncthreads();
        }
    }
    float* Cf = (float*)Cv; ushort_t* Cb = (ushort_t*)Cv;
    const int mr = m0 + w*16 + kg*4;
    const int nc = n0 + ml;
    #pragma unroll
    for (int f = 0; f < 4; ++f) {
        const int n = nc + f*16;
        const float bs = (EPI != 2) ? bias[n] : 0.0f;
        #pragma unroll
        for (int r = 0; r < 4; ++r) {
            float x = acc[f][r] + bs;
            if (EPI == 1) x = gelu_f(x);
            if (EPI == 2) x = acc[f][r] + Add[(long)(mr + r)*ldadd + n];
            if (OUTBF) Cb[(long)(mr + r)*ldc + n] = f2bf(x);
            else       Cf[(long)(mr + r)*ldc + n] = x;
        }
    }
}

// ---------------- control: f = [sf(256), cf(128)] bf16 ----------------
__device__ void control_dev(char* smem, int b, const Ptrs& p)
{
    float* bc  = (float*)smem;        // 8
    float* cf1 = bc + 8;              // 64
    const int tid = threadIdx.x;
    if (tid < 6) bc[tid] = p.BC[b*6 + tid];
    __syncthreads();
    {
        int s = tid >> 6;
        p.fbuf_bf[(long)b*384 + tid] = f2bf(gelu_f(bc[s]*p.sb_w[tid] + p.sb_b[tid]));
    }
    if (tid < 64) {
        cf1[tid] = gelu_f(bc[4]*p.cm_w1[tid] + bc[5]*p.cm_w1[64+tid] + p.cm_b1[tid]);
    }
    __syncthreads();
    if (tid < 128) {
        float acc = p.cm_b2[tid];
        #pragma unroll 8
        for (int i = 0; i < 64; ++i) acc = fmaf(cf1[i], p.cm_w2[i*128 + tid], acc);
        p.fbuf_bf[(long)b*384 + 256 + tid] = f2bf(gelu_f(acc));
    }
}

// ---------------- a_map = LN(relu(a_n @ a0_w + a0_b)) bf16 ----------------
__device__ void a_map_dev(char* smem, int bx, int v, const Ptrs& p)
{
    float* arow = (float*)smem;       // [4][64]
    const int w = threadIdx.x >> 6, lane = threadIdx.x & 63;
    const int b = bx*4 + w;
    arow[w*64 + lane] = p.a_n[((long)b*2 + v)*64 + lane];
    __syncthreads();
    float acc = p.a0_b[v*64 + lane];
    #pragma unroll 8
    for (int rp = 0; rp < 64; ++rp)
        acc = fmaf(arow[w*64 + rp], p.a0_w[((long)v*64 + rp)*64 + lane], acc);
    float x = fmaxf(acc, 0.0f);
    float mu = wave_sum(x) * (1.0f/64.0f);
    float d = x - mu;
    float var = wave_sum(d*d) * (1.0f/64.0f);
    float y = d * rsqrtf(var + 1e-5f) * p.a0_ln_g[v*64 + lane] + p.a0_ln_b[v*64 + lane];
    p.amap_bf[((long)v*512 + b)*64 + lane] = f2bf(y);
}

// ---------------- KV[v,h,k,l] = sum_r K[v,r,h*64+k]*V[v,r,h*64+l] ----------------
__device__ void kv_outer_dev(char* smem, int z, const Ptrs& p)
{
    const int v = z >> 3, h = z & 7;
    float* Ks = (float*)smem;         // [64][64]
    float* Vs = Ks + 4096;
    const int tid = threadIdx.x;
    for (int idx = tid; idx < 4096; idx += 256) {
        int r = idx >> 6, c = idx & 63;
        long off = ((long)v*64 + r)*512 + h*64 + c;
        Ks[idx] = p.Kws[off];
        Vs[idx] = p.Vws[off];
    }
    __syncthreads();
    const int tx = tid & 15, ty = tid >> 4;
    float acc[4][4] = {};
    #pragma unroll 4
    for (int r = 0; r < 64; ++r) {
        float a[4], bb[4];
        #pragma unroll
        for (int i = 0; i < 4; ++i) a[i] = Ks[r*64 + ty*4+i];
        #pragma unroll
        for (int j = 0; j < 4; ++j) bb[j] = Vs[r*64 + tx*4+j];
        #pragma unroll
        for (int i = 0; i < 4; ++i)
            #pragma unroll
            for (int j = 0; j < 4; ++j)
                acc[i][j] = fmaf(a[i], bb[j], acc[i][j]);
    }
    #pragma unroll
    for (int i = 0; i < 4; ++i)
        #pragma unroll
        for (int j = 0; j < 4; ++j)
            p.KV[(((long)v*8 + h)*64 + ty*4+i)*64 + tx*4+j] = acc[i][j];
}

// ---------------- attention constants (partials per e-chunk) ----------------
__device__ void attn_parts_dev(char* smem, int v, int ec, const Ptrs& p)
{
    float* Pv  = (float*)smem;        // 512
    float* Qv  = Pv + 512;            // 512
    float* red = Qv + 512;            // 2*256
    const int tid = threadIdx.x;
    for (int dp = tid; dp < 512; dp += 256) {
        int h = dp >> 6, l = dp & 63;
        const float* kvp = p.KV + ((long)(v*8 + h)*64)*64 + l;
        const float* wq = p.Wq_w + v*512 + h*64;
        const float* wb = p.Wq_b + v*512 + h*64;
        float pp = 0.f, q = 0.f;
        #pragma unroll 8
        for (int k = 0; k < 64; ++k) {
            float kv = kvp[(long)k*64];
            pp = fmaf(wq[k], kv, pp);
            q  = fmaf(wb[k], kv, q);
        }
        Pv[dp] = pp; Qv[dp] = q;
    }
    __syncthreads();
    const int e = ec*64 + (tid & 63);
    const int qd = tid >> 6;
    float pw = 0.f, qw = 0.f;
    const float* owp = p.attn_ow + (long)v*512*512 + e;
    #pragma unroll 8
    for (int d = qd*128; d < qd*128 + 128; ++d) {
        float wv = owp[(long)d*512];
        pw = fmaf(Pv[d], wv, pw);
        qw = fmaf(Qv[d], wv, qw);
    }
    red[tid] = pw; red[256 + tid] = qw;
    __syncthreads();
    if (tid < 64) {
        float PW = red[tid] + red[tid+64] + red[tid+128] + red[tid+192];
        float QW = red[256+tid] + red[256+tid+64] + red[256+tid+128] + red[256+tid+192];
        QW += p.attn_ob[v*512 + ec*64 + tid];
        float pj = p.proj_w[v*512 + ec*64 + tid];
        float pc1 = wave_sum(PW*pj);
        float pc0 = wave_sum(QW*pj);
        if (tid == 0) {
            p.parts[v*8 + ec]      = pc1;
            p.parts[16 + v*8 + ec] = pc0;
        }
    }
}

// ---------------- ofuse ----------------
__device__ void ofuse_dev(char* smem, int bx, int v, const Ptrs& p)
{
    float* hrow = (float*)smem;       // [4][512]
    const int w = threadIdx.x >> 6, lane = threadIdx.x & 63;
    const int b = bx*4 + w;
    const ushort_t* h2p = p.h2_bf + ((long)v*512 + b)*512;
    #pragma unroll
    for (int i = 0; i < 8; ++i) hrow[w*512 + lane + i*64] = bf2f(h2p[lane + i*64]);
    __syncthreads();
    float acc = p.ffn_b3[v*64 + lane];
    const float* w3p = p.ffn_w3 + (long)v*512*64 + lane;
    #pragma unroll 8
    for (int d = 0; d < 512; ++d)
        acc = fmaf(hrow[w*512 + d], w3p[(long)d*64], acc);
    const float am = bf2f(p.amap_bf[((long)v*512 + b)*64 + lane]);
    float t = acc + am;
    float mu = wave_sum(t) * (1.0f/64.0f);
    float dd = t - mu;
    float var = wave_sum(dd*dd) * (1.0f/64.0f);
    float u = dd * rsqrtf(var + 1e-5f) * p.ffn_ln_g[v*64+lane] + p.ffn_ln_b[v*64+lane];
    float s1 = 0.f, s0 = 0.f;
    #pragma unroll
    for (int c = 0; c < 8; ++c) { s1 += p.parts[v*8 + c]; s0 += p.parts[16 + v*8 + c]; }
    const float inv = 0.044194173824159216f;   // 1/sqrt(512)
    const float c1 = s1*inv, c0 = s0*inv + p.proj_b[v];
    p.anext_bf[((long)v*512 + b)*64 + lane] = f2bf(am*(1.0f + c1) + c0 + p.alpha[v]*u);
}

// ================= stage kernels =================
__global__ __launch_bounds__(256) void stage0_k(Ptrs p, CvtArgs ca, int ncvt)
{
    extern __shared__ char smem[];
    const int bx = blockIdx.x;
    if (bx < ncvt) {
        int e = 0;
        while (bx >= ca.cum[e+1]) ++e;
        cvt_dev(smem, bx - ca.cum[e], ca.d[e]);
    } else if (bx < ncvt + 512) {
        control_dev(smem, bx - ncvt, p);
    } else {
        int i = bx - ncvt - 512;              // 256: v*128 + bx4
        a_map_dev(smem, i & 127, i >> 7, p);
    }
}

__global__ __launch_bounds__(256) void stage1_k(Ptrs p)
{
    extern __shared__ char smem[];
    const int bx = blockIdx.x;
    if (bx < 32) {                            // fu1: M=512,N=256,K=384
        int by = bx >> 2, bxx = bx & 3;
        bgemm_dev(smem, p.fbuf_bf, p.w_fu1t, p.fu_b1, nullptr, p.hA_bf,
                  by*64, bxx*64, 384, 256, 0, 1, true);
    } else if (bx < 160) {                    // ffn1: per-v M=512,N=512,K=64
        int i = bx - 32; int v = i >> 6; i &= 63; int by = i >> 3, bxx = i & 7;
        bgemm_dev(smem, p.amap_bf + (long)v*32768, p.w_ffn1t + (long)v*32768,
                  p.ffn_b1 + v*512, nullptr, (void*)(p.h1_bf + (long)v*262144),
                  by*64, bxx*64, 64, 512, 0, 1, true);
    } else {                                  // kv: 32 blocks (which, v, ntile)
        int i = bx - 160; int which = i >> 4; int v = (i >> 3) & 1; int bxx = i & 7;
        const ushort_t* Wt = which ? p.Wv_t : p.Wk_t;
        const float* Wb = which ? p.Wv_b : p.Wk_b;
        float* C = which ? p.Vws : p.Kws;
        bgemm_dev(smem, p.Phi_t + (long)v*65536, Wt + (long)v*524288,
                  Wb + v*512, nullptr, (void*)(C + (long)v*32768),
                  0, bxx*64, 1024, 512, 0, 0, false);
    }
}

__global__ __launch_bounds__(256) void stage2_k(Ptrs p)
{
    extern __shared__ char smem[];
    const int bx = blockIdx.x;
    if (bx < 64) {                            // fu2: M=512,N=512,K=256
        int by = bx >> 3, bxx = bx & 7;
        bgemm_dev(smem, p.hA_bf, p.w_fu2t, p.fu_b2, nullptr, p.hB_bf,
                  by*64, bxx*64, 256, 512, 0, 1, true);
    } else if (bx < 192) {                    // ffn2: per-v M=512,N=512,K=512
        int i = bx - 64; int v = i >> 6; i &= 63; int by = i >> 3, bxx = i & 7;
        bgemm_dev(smem, p.h1_bf + (long)v*262144, p.w_ffn2t + (long)v*262144,
                  p.ffn_b2 + v*512, nullptr, (void*)(p.h2_bf + (long)v*262144),
                  by*64, bxx*64, 512, 512, 0, 1, true);
    } else {                                  // kv_outer: 16 blocks
        kv_outer_dev(smem, bx - 192, p);
    }
}

__global__ __launch_bounds__(256) void stage3_k(Ptrs p)
{
    extern __shared__ char smem[];
    const int bx = blockIdx.x;
    if (bx < 32) {                            // fu3: M=512,N=256,K=512
        int by = bx >> 2, bxx = bx & 3;
        bgemm_dev(smem, p.hB_bf, p.w_fu3t, p.fu_b3, nullptr, p.hC_bf,
                  by*64, bxx*64, 512, 256, 0, 1, true);
    } else {                                  // attn_parts: 16 blocks (v, ec)
        int i = bx - 32;
        attn_parts_dev(smem, i & 1, i >> 1, p);
    }
}

__global__ __launch_bounds__(256) void stage4_k(Ptrs p)
{
    extern __shared__ char smem[];
    const int bx = blockIdx.x;
    if (bx < 256) {                           // fu4: M=512,N=2048,K=256 (fp32 out)
        int by = bx >> 5, bxx = bx & 31;
        bgemm_dev(smem, p.hC_bf, p.w_fu4t, p.fu_b4, nullptr, p.UB,
                  by*64, bxx*64, 256, 2048, 0, 0, false);
    } else {                                  // ofuse: 256 blocks
        int i = bx - 256;
        ofuse_dev(smem, i & 127, i >> 7, p);
    }
}

__global__ __launch_bounds__(256) void stage5_k(Ptrs p)
{
    extern __shared__ char smem[];
    const int bx = blockIdx.x;                // uhat: per-v M=512,N=1024,K=64
    int v = bx >> 7; int rem = bx & 127; int by = rem >> 4, bxx = rem & 15;
    bgemm_dev(smem, p.anext_bf + (long)v*32768, p.Phi_bf + (long)v*65536,
              nullptr, p.UB + v*1024, (void*)(p.out + v*1024),
              by*64, bxx*64, 64, 2048, 2048, 2, false);
}

extern "C" void kernel_launch(void* const* d_in, const int* in_sizes, int n_in,
                              void* d_out, int out_size, void* d_ws, size_t ws_size,
                              hipStream_t stream)
{
    const float* a_n      = (const float*)d_in[0];
    const float* BC       = (const float*)d_in[1];
    const float* Phi      = (const float*)d_in[2];
    const float* Wq_w     = (const float*)d_in[3];
    const float* Wq_b     = (const float*)d_in[4];
    const float* Wk_w     = (const float*)d_in[5];
    const float* Wk_b     = (const float*)d_in[6];
    const float* Wv_w     = (const float*)d_in[7];
    const float* Wv_b     = (const float*)d_in[8];
    const float* attn_ow  = (const float*)d_in[9];
    const float* attn_ob  = (const float*)d_in[10];
    const float* proj_w   = (const float*)d_in[11];
    const float* proj_b   = (const float*)d_in[12];
    const float* ffn_w1   = (const float*)d_in[13];
    const float* ffn_b1   = (const float*)d_in[14];
    const float* ffn_w2   = (const float*)d_in[15];
    const float* ffn_b2   = (const float*)d_in[16];
    const float* ffn_w3   = (const float*)d_in[17];
    const float* ffn_b3   = (const float*)d_in[18];
    const float* ffn_ln_g = (const float*)d_in[19];
    const float* ffn_ln_b = (const float*)d_in[20];
    const float* a0_w     = (const float*)d_in[21];
    const float* a0_b     = (const float*)d_in[22];
    const float* a0_ln_g  = (const float*)d_in[23];
    const float* a0_ln_b  = (const float*)d_in[24];
    const float* alpha    = (const float*)d_in[25];
    const float* sb_w     = (const float*)d_in[26];
    const float* sb_b     = (const float*)d_in[27];
    const float* cm_w1    = (const float*)d_in[28];
    const float* cm_b1    = (const float*)d_in[29];
    const float* cm_w2    = (const float*)d_in[30];
    const float* cm_b2    = (const float*)d_in[31];
    const float* fu_w1    = (const float*)d_in[32];
    const float* fu_b1    = (const float*)d_in[33];
    const float* fu_w2    = (const float*)d_in[34];
    const float* fu_b2    = (const float*)d_in[35];
    const float* fu_w3    = (const float*)d_in[36];
    const float* fu_b3    = (const float*)d_in[37];
    const float* fu_w4    = (const float*)d_in[38];
    const float* fu_b4    = (const float*)d_in[39];

    float* ws = (float*)d_ws;
    Ptrs p;
    p.a_n = a_n; p.BC = BC; p.Wq_w = Wq_w; p.Wq_b = Wq_b; p.Wk_b = Wk_b; p.Wv_b = Wv_b;
    p.attn_ow = attn_ow; p.attn_ob = attn_ob; p.proj_w = proj_w; p.proj_b = proj_b;
    p.ffn_w3 = ffn_w3; p.ffn_b3 = ffn_b3; p.ffn_ln_g = ffn_ln_g; p.ffn_ln_b = ffn_ln_b;
    p.a0_w = a0_w; p.a0_b = a0_b; p.a0_ln_g = a0_ln_g; p.a0_ln_b = a0_ln_b;
    p.alpha = alpha; p.sb_w = sb_w; p.sb_b = sb_b;
    p.cm_w1 = cm_w1; p.cm_b1 = cm_b1; p.cm_w2 = cm_w2; p.cm_b2 = cm_b2;
    p.fu_b1 = fu_b1; p.fu_b2 = fu_b2; p.fu_b3 = fu_b3; p.fu_b4 = fu_b4;
    p.ffn_b1 = ffn_b1; p.ffn_b2 = ffn_b2;

    p.Kws      = ws;                             // 65536
    p.Vws      = ws + 65536;                     // 65536
    p.KV       = ws + 131072;                    // 65536
    p.parts    = ws + 196608;                    // 64
    p.amap_bf  = (ushort_t*)(ws + 196736);       // 65536 bf16
    p.anext_bf = (ushort_t*)(ws + 229504);       // 65536
    p.h1_bf    = (ushort_t*)(ws + 262272);       // 524288
    p.h2_bf    = (ushort_t*)(ws + 524416);       // 524288
    p.fbuf_bf  = (ushort_t*)(ws + 786560);       // 196608
    p.hA_bf    = (ushort_t*)(ws + 884864);       // 131072
    p.hB_bf    = (ushort_t*)(ws + 950400);       // 262144
    p.hC_bf    = (ushort_t*)(ws + 1081472);      // 131072
    p.w_fu1t   = (ushort_t*)(ws + 1147008);      // 98304  [256][384]
    p.w_fu2t   = (ushort_t*)(ws + 1196160);      // 131072 [512][256]
    p.w_fu3t   = (ushort_t*)(ws + 1261696);      // 131072 [256][512]
    p.w_fu4t   = (ushort_t*)(ws + 1327232);      // 524288 [2048][256]
    p.w_ffn1t  = (ushort_t*)(ws + 1589376);      // 65536  [v][512][64]
    p.w_ffn2t  = (ushort_t*)(ws + 1622144);      // 524288 [v][512][512]
    p.Phi_bf   = (ushort_t*)(ws + 1884288);      // 131072 [v][1024][64]
    p.UB       = ws + 1949824;                   // 1048576 fp32 [512][2048]
    p.Wk_t     = (ushort_t*)p.UB;                // alias (consumed in S1, UB written S4)
    p.Wv_t     = ((ushort_t*)p.UB) + 1048576;
    p.Phi_t    = (ushort_t*)(ws + 2998400);      // 131072 [v][64][1024]
    p.out      = (float*)d_out;

    CvtArgs ca;
    auto set = [&](int i, const float* s, ushort_t* dst, int K, int N, int flat) {
        ca.d[i].src = s; ca.d[i].dst = dst; ca.d[i].K = K; ca.d[i].N = N; ca.d[i].flat = flat;
    };
    set(0,  fu_w1,           p.w_fu1t,           384, 256,  0);
    set(1,  fu_w2,           p.w_fu2t,           256, 512,  0);
    set(2,  fu_w3,           p.w_fu3t,           512, 256,  0);
    set(3,  fu_w4,           p.w_fu4t,           256, 2048, 0);
    set(4,  ffn_w1,          p.w_ffn1t,          64,  512,  0);
    set(5,  ffn_w1 + 32768,  p.w_ffn1t + 32768,  64,  512,  0);
    set(6,  ffn_w2,          p.w_ffn2t,          512, 512,  0);
    set(7,  ffn_w2 + 262144, p.w_ffn2t + 262144, 512, 512,  0);
    set(8,  Phi,             p.Phi_bf,           131072, 0, 1);
    set(9,  Phi,             p.Phi_t,            1024, 64,  0);
    set(10, Phi + 65536,     p.Phi_t + 65536,    1024, 64,  0);
    set(11, Wk_w,            p.Wk_t,             1024, 512, 0);
    set(12, Wk_w + 524288,   p.Wk_t + 524288,    1024, 512, 0);
    set(13, Wv_w,            p.Wv_t,             1024, 512, 0);
    set(14, Wv_w + 524288,   p.Wv_t + 524288,    1024, 512, 0);
    const int tl[15] = {96,128,128,512,32,32,256,256,32,64,64,512,512,512,512};
    ca.cum[0] = 0;
    for (int i = 0; i < 15; ++i) ca.cum[i+1] = ca.cum[i] + tl[i];
    const int ncvt = ca.cum[15];                 // 3648

    stage0_k<<<ncvt + 768, 256, 4352,  stream>>>(p, ca, ncvt);
    stage1_k<<<192,        256, 20480, stream>>>(p);
    stage2_k<<<208,        256, 32768, stream>>>(p);
    stage3_k<<<48,         256, 20480, stream>>>(p);
    stage4_k<<<512,        256, 20480, stream>>>(p);
    stage5_k<<<256,        256, 20480, stream>>>(p);
}